// Round 9
// baseline (255.427 us; speedup 1.0000x reference)
//
#include <hip/hip_runtime.h>

typedef float f32x4 __attribute__((ext_vector_type(4)));
typedef float f32x2 __attribute__((ext_vector_type(2)));
typedef __bf16 bf16x8 __attribute__((ext_vector_type(8)));
typedef __bf16 bf16x4 __attribute__((ext_vector_type(4)));
typedef short short4v __attribute__((ext_vector_type(4)));
typedef short short8v __attribute__((ext_vector_type(8)));

#define MFMA32K(a, b, c) __builtin_amdgcn_mfma_f32_16x16x32_bf16((a), (b), (c), 0, 0, 0)
#define MFMA16K(a, b, c) __builtin_amdgcn_mfma_f32_16x16x16bf16_1k((a), (b), (c), 0, 0, 0)
#define CFENCE() asm volatile("" ::: "memory")
#define DSFENCE() asm volatile("s_waitcnt lgkmcnt(0)" ::: "memory")

constexpr int Tn = 4096, Cn = 512, Hn = 64;
constexpr float QSCALE = 1.4426950408889634f * 0.04419417382415922f;
constexpr float M0 = -30000.0f;

// keep-alive sinks (rule #17): zero-instruction, forces value liveness
__device__ __forceinline__ void keepf4(f32x4 x) { asm volatile("" :: "v"(x)); }
__device__ __forceinline__ void keepf2(f32x2 x) { asm volatile("" :: "v"(x)); }

// ---------------- kernel 0: W fp32 -> bf16 (Wq pre-scaled) ----------------
__global__ void wconv(const float* __restrict__ Wq, const float* __restrict__ Wk,
                      const float* __restrict__ Wv, __bf16* __restrict__ Wb) {
    int t = blockIdx.y;
    int i = blockIdx.x * 256 + threadIdx.x;
    const float* src = (t == 0) ? Wq : (t == 1) ? Wk : Wv;
    float scale = (t == 0) ? QSCALE : 1.0f;
    Wb[t * Hn * Cn + i] = (__bf16)(src[i] * scale);
}

__device__ inline bf16x8 cvt8(float4 u0, float4 u1) {
    bf16x8 r;
    r[0] = (__bf16)u0.x; r[1] = (__bf16)u0.y; r[2] = (__bf16)u0.z; r[3] = (__bf16)u0.w;
    r[4] = (__bf16)u1.x; r[5] = (__bf16)u1.y; r[6] = (__bf16)u1.z; r[7] = (__bf16)u1.w;
    return r;
}

// ---------------- kernel 1: QKV projection, split-K x4 (frozen) ------------
__global__ __launch_bounds__(512, 4) void proj(const float* __restrict__ x,
                                               const __bf16* __restrict__ Wb,
                                               __bf16* __restrict__ Qb,
                                               __bf16* __restrict__ Kb,
                                               __bf16* __restrict__ VF) {
    const int tid = threadIdx.x;
    const int lane = tid & 63, wid = tid >> 6;
    const int rg = wid >> 2, kc = wid & 3;
    const int c = lane & 15, h = lane >> 4;
    const int row0 = blockIdx.x * 32 + rg * 16;

    __shared__ float sl[2][3][64][48];
    __shared__ __bf16 tb[2][16][72];

    f32x4 acc[3][4] = {};
    const float* xr = x + (size_t)(row0 + c) * Cn + kc * 128;
    const __bf16* wr = Wb + kc * 128 + 8 * h;

#pragma unroll
    for (int it = 0; it < 4; ++it) {
        const int kb = it * 32 + 8 * h;
        const float4* p0 = (const float4*)(xr + kb);
        bf16x8 a0 = cvt8(p0[0], p0[1]);
#pragma unroll
        for (int w = 0; w < 3; ++w)
#pragma unroll
            for (int nt = 0; nt < 4; ++nt) {
                bf16x8 bf = *(const bf16x8*)(wr + (size_t)(w * Hn + nt * 16 + c) * Cn + it * 32);
                acc[w][nt] = MFMA32K(a0, bf, acc[w][nt]);
            }
    }

    if (kc) {
#pragma unroll
        for (int w = 0; w < 3; ++w)
#pragma unroll
            for (int nt = 0; nt < 4; ++nt)
                *(f32x4*)&sl[rg][kc - 1][lane][(w * 4 + nt) * 4] = acc[w][nt];
    }
    __syncthreads();
    if (!kc) {
#pragma unroll
        for (int j = 0; j < 3; ++j)
#pragma unroll
            for (int w = 0; w < 3; ++w)
#pragma unroll
                for (int nt = 0; nt < 4; ++nt)
                    acc[w][nt] += *(const f32x4*)&sl[rg][j][lane][(w * 4 + nt) * 4];

#pragma unroll
        for (int w = 0; w < 2; ++w) {
            CFENCE();
#pragma unroll
            for (int nt = 0; nt < 4; ++nt)
#pragma unroll
                for (int r = 0; r < 4; ++r)
                    tb[rg][h * 4 + r][nt * 16 + c] = (__bf16)acc[w][nt][r];
            DSFENCE();
            __bf16* dst = (w == 0) ? Qb : Kb;
#pragma unroll
            for (int ch = 0; ch < 2; ++ch) {
                int rr = ch * 8 + (lane >> 3);
                bf16x8 vv = *(const bf16x8*)(&tb[rg][rr][(lane & 7) * 8]);
                *(bf16x8*)(dst + (size_t)(row0 + rr) * Hn + (lane & 7) * 8) = vv;
            }
            CFENCE();
        }

        const int b = row0 >> 12;
        const int t0 = row0 & (Tn - 1);
        const int tile = t0 >> 4;
#pragma unroll
        for (int nt = 0; nt < 4; ++nt) {
            f32x4 a = acc[2][nt];
            bf16x4 v4;
            v4[0] = (__bf16)a.x; v4[1] = (__bf16)a.y;
            v4[2] = (__bf16)a.z; v4[3] = (__bf16)a.w;
            size_t off = ((size_t)((b * 256 + tile) * 4 + h) * 64 + (nt * 16 + c)) * 4;
            *(bf16x4*)(VF + off) = v4;
        }
    }
}

// ---------------- kernel 2: causal flash attention (frozen from R8) --------
__global__ __launch_bounds__(512, 4) void attn(const __bf16* __restrict__ Qb,
                                               const __bf16* __restrict__ Kb,
                                               const __bf16* __restrict__ VF,
                                               float* __restrict__ out) {
    const int tid = threadIdx.x;
    const int lane = tid & 63, ks = tid >> 6;
    const int c = lane & 15, h = lane >> 4;
    const int b = blockIdx.x & 3;
    const int vg = 127 - (int)(blockIdx.x >> 2);
    const int qbase = vg * 32;
    const int nkv = vg / 2 + 1;

    const __bf16* Kbase = Kb + (size_t)b * Tn * Hn;
    const __bf16* Vbase = VF + (size_t)b * 256 * 1024;

    __shared__ float Mo[4][64][36];
    __shared__ float Mml[4][64][4];

    bf16x8 qf[2][2];
#pragma unroll
    for (int qs = 0; qs < 2; ++qs) {
        const __bf16* qp = Qb + (size_t)(b * Tn + qbase + qs * 16 + c) * Hn;
        qf[qs][0] = *(const bf16x8*)(qp + 8 * h);
        qf[qs][1] = *(const bf16x8*)(qp + 32 + 8 * h);
    }

    f32x4 o[2][4] = {};
    float m[2] = {M0, M0};
    float l[2] = {};

    for (int kt = ks; kt < nkv; kt += 8) {
        const int j0 = kt * 64;
        f32x4 s[2][4];
        {
            bf16x8 kf[4][2];
#pragma unroll
            for (int ct = 0; ct < 4; ++ct) {
                const __bf16* kp = Kbase + (size_t)(j0 + ct * 16 + c) * Hn;
                kf[ct][0] = *(const bf16x8*)(kp + 8 * h);
                kf[ct][1] = *(const bf16x8*)(kp + 32 + 8 * h);
            }
#pragma unroll
            for (int qs = 0; qs < 2; ++qs)
#pragma unroll
                for (int ct = 0; ct < 4; ++ct) {
                    f32x4 z = {};
                    z = MFMA32K(kf[ct][0], qf[qs][0], z);
                    z = MFMA32K(kf[ct][1], qf[qs][1], z);
                    s[qs][ct] = z;
                }
        }
        const __bf16* vt = Vbase + ((size_t)(j0 >> 4) << 10) + (h << 8);
        short4v vf0[2][4];
#pragma unroll
        for (int dt = 0; dt < 2; ++dt)
#pragma unroll
            for (int ct = 0; ct < 4; ++ct)
                vf0[dt][ct] = *(const short4v*)(vt + (ct << 10) + ((dt * 16 + c) << 2));

        const bool diag = (kt == nkv - 1);
        short4v pf[2][4];
#pragma unroll
        for (int qs = 0; qs < 2; ++qs) {
            if (diag) {
#pragma unroll
                for (int ct = 0; ct < 4; ++ct)
#pragma unroll
                    for (int r = 0; r < 4; ++r)
                        if (j0 + ct * 16 + 4 * h + r > qbase + qs * 16 + c)
                            s[qs][ct][r] = -1e30f;
            }
            float lm = fmaxf(fmaxf(fmaxf(s[qs][0][0], s[qs][0][1]), fmaxf(s[qs][0][2], s[qs][0][3])),
                             fmaxf(fmaxf(s[qs][1][0], s[qs][1][1]), fmaxf(s[qs][1][2], s[qs][1][3])));
            lm = fmaxf(lm, fmaxf(fmaxf(fmaxf(s[qs][2][0], s[qs][2][1]), fmaxf(s[qs][2][2], s[qs][2][3])),
                                 fmaxf(fmaxf(s[qs][3][0], s[qs][3][1]), fmaxf(s[qs][3][2], s[qs][3][3]))));
            if (!__all(lm <= m[qs] + 8.0f)) {
                float rm = fmaxf(lm, __shfl_xor(lm, 16));
                rm = fmaxf(rm, __shfl_xor(rm, 32));
                float mn = fmaxf(m[qs], rm);
                float sc = __builtin_amdgcn_exp2f(m[qs] - mn);
                m[qs] = mn;
                l[qs] *= sc;
#pragma unroll
                for (int dt = 0; dt < 4; ++dt) o[qs][dt] *= sc;
            }
            float lsum = 0.0f;
#pragma unroll
            for (int ct = 0; ct < 4; ++ct) {
                bf16x4 pb;
#pragma unroll
                for (int r = 0; r < 4; ++r) {
                    float p = __builtin_amdgcn_exp2f(s[qs][ct][r] - m[qs]);
                    lsum += p;
                    pb[r] = (__bf16)p;
                }
                pf[qs][ct] = __builtin_bit_cast(short4v, pb);
            }
            l[qs] += lsum;
        }
#pragma unroll
        for (int qs = 0; qs < 2; ++qs)
#pragma unroll
            for (int dt = 0; dt < 2; ++dt)
#pragma unroll
                for (int ct = 0; ct < 4; ++ct)
                    o[qs][dt] = MFMA16K(vf0[dt][ct], pf[qs][ct], o[qs][dt]);
        short4v vf1[2][4];
#pragma unroll
        for (int dt = 0; dt < 2; ++dt)
#pragma unroll
            for (int ct = 0; ct < 4; ++ct)
                vf1[dt][ct] = *(const short4v*)(vt + (ct << 10) + (((dt + 2) * 16 + c) << 2));
#pragma unroll
        for (int qs = 0; qs < 2; ++qs)
#pragma unroll
            for (int dt = 0; dt < 2; ++dt)
#pragma unroll
                for (int ct = 0; ct < 4; ++ct)
                    o[qs][dt + 2] = MFMA16K(vf1[dt][ct], pf[qs][ct], o[qs][dt + 2]);
    }

#pragma unroll
    for (int qs = 0; qs < 2; ++qs) {
        l[qs] += __shfl_xor(l[qs], 16);
        l[qs] += __shfl_xor(l[qs], 32);
    }

#pragma unroll
    for (int step = 4; step >= 1; step >>= 1) {
        if (ks >= step && ks < 2 * step) {
            int slot = ks - step;
#pragma unroll
            for (int qs = 0; qs < 2; ++qs) {
                Mml[slot][lane][qs] = m[qs];
                Mml[slot][lane][2 + qs] = l[qs];
#pragma unroll
                for (int dt = 0; dt < 4; ++dt)
                    *(f32x4*)&Mo[slot][lane][(qs * 4 + dt) * 4] = o[qs][dt];
            }
        }
        __syncthreads();
        if (ks < step) {
#pragma unroll
            for (int qs = 0; qs < 2; ++qs) {
                float m2 = Mml[ks][lane][qs];
                float l2 = Mml[ks][lane][2 + qs];
                float M = fmaxf(m[qs], m2);
                float e1 = __builtin_amdgcn_exp2f(m[qs] - M);
                float e2 = __builtin_amdgcn_exp2f(m2 - M);
                m[qs] = M;
                l[qs] = l[qs] * e1 + l2 * e2;
#pragma unroll
                for (int dt = 0; dt < 4; ++dt) {
                    f32x4 o2 = *(const f32x4*)&Mo[ks][lane][(qs * 4 + dt) * 4];
                    o[qs][dt] = o[qs][dt] * e1 + o2 * e2;
                }
            }
        }
        __syncthreads();
    }

    if (ks == 0) {
#pragma unroll
        for (int qs = 0; qs < 2; ++qs) {
            float rl = 1.0f / l[qs];
            float* ob = out + ((size_t)(b * Tn + qbase + qs * 16 + c)) * Hn;
#pragma unroll
            for (int dt = 0; dt < 4; ++dt) {
                f32x4 w = o[qs][dt] * rl;
                *(f32x4*)(ob + dt * 16 + 4 * h) = w;
            }
        }
    }
}

// ---------------- ablation variants (write to recomputed ws scratch) -------
// MODE 0=A loads-only, 1=B +QK, 2=C +softmax(always-rescale), 3=E compute-only
// (hoisted operands, per-iter XOR perturb to defeat LICM). No merge epilogue;
// 4B/thread scratch write. Cost is data-independent (no defer-max branch).
template<int MODE>
__global__ __launch_bounds__(512, 4) void attn_abl(const __bf16* __restrict__ Qb,
                                                   const __bf16* __restrict__ Kb,
                                                   const __bf16* __restrict__ VF,
                                                   float* scratch) {
    const int tid = threadIdx.x;
    const int lane = tid & 63, ks = tid >> 6;
    const int c = lane & 15, h = lane >> 4;
    const int b = blockIdx.x & 3;
    const int vg = 127 - (int)(blockIdx.x >> 2);
    const int qbase = vg * 32;
    const int nkv = vg / 2 + 1;

    const __bf16* Kbase = Kb + (size_t)b * Tn * Hn;
    const __bf16* Vbase = VF + (size_t)b * 256 * 1024;

    bf16x8 qf[2][2];
#pragma unroll
    for (int qs = 0; qs < 2; ++qs) {
        const __bf16* qp = Qb + (size_t)(b * Tn + qbase + qs * 16 + c) * Hn;
        qf[qs][0] = *(const bf16x8*)(qp + 8 * h);
        qf[qs][1] = *(const bf16x8*)(qp + 32 + 8 * h);
    }

    f32x4 o[2][4] = {};
    float m[2] = {M0, M0};
    float l[2] = {};

    bf16x8 kfH[4][2];
    short4v vfH[4][4];
    if constexpr (MODE == 3) {
        const int kt0 = (ks < nkv) ? ks : nkv - 1;
        const int j0 = kt0 * 64;
#pragma unroll
        for (int ct = 0; ct < 4; ++ct) {
            const __bf16* kp = Kbase + (size_t)(j0 + ct * 16 + c) * Hn;
            kfH[ct][0] = *(const bf16x8*)(kp + 8 * h);
            kfH[ct][1] = *(const bf16x8*)(kp + 32 + 8 * h);
        }
        const __bf16* vt = Vbase + ((size_t)(j0 >> 4) << 10) + (h << 8);
#pragma unroll
        for (int dt = 0; dt < 4; ++dt)
#pragma unroll
            for (int ct = 0; ct < 4; ++ct)
                vfH[dt][ct] = *(const short4v*)(vt + (ct << 10) + ((dt * 16 + c) << 2));
    }

    for (int kt = ks; kt < nkv; kt += 8) {
        const int j0 = kt * 64;
        bf16x8 kf[4][2];
        short4v vf[4][4];
        if constexpr (MODE == 3) {
            const short p = (short)(kt & 1);   // defeat LICM, 24 xor/iter
#pragma unroll
            for (int ct = 0; ct < 4; ++ct)
#pragma unroll
                for (int j = 0; j < 2; ++j) {
                    short8v t = __builtin_bit_cast(short8v, kfH[ct][j]);
                    t[0] ^= p;
                    kf[ct][j] = __builtin_bit_cast(bf16x8, t);
                }
#pragma unroll
            for (int dt = 0; dt < 4; ++dt)
#pragma unroll
                for (int ct = 0; ct < 4; ++ct) {
                    short4v t = vfH[dt][ct];
                    t[0] ^= p;
                    vf[dt][ct] = t;
                }
        } else {
#pragma unroll
            for (int ct = 0; ct < 4; ++ct) {
                const __bf16* kp = Kbase + (size_t)(j0 + ct * 16 + c) * Hn;
                kf[ct][0] = *(const bf16x8*)(kp + 8 * h);
                kf[ct][1] = *(const bf16x8*)(kp + 32 + 8 * h);
            }
            const __bf16* vt = Vbase + ((size_t)(j0 >> 4) << 10) + (h << 8);
#pragma unroll
            for (int dt = 0; dt < 4; ++dt)
#pragma unroll
                for (int ct = 0; ct < 4; ++ct)
                    vf[dt][ct] = *(const short4v*)(vt + (ct << 10) + ((dt * 16 + c) << 2));
        }

        if constexpr (MODE == 0) {
#pragma unroll
            for (int ct = 0; ct < 4; ++ct) {
                keepf4(__builtin_bit_cast(f32x4, kf[ct][0]));
                keepf4(__builtin_bit_cast(f32x4, kf[ct][1]));
            }
#pragma unroll
            for (int dt = 0; dt < 4; ++dt)
#pragma unroll
                for (int ct = 0; ct < 4; ++ct)
                    keepf2(__builtin_bit_cast(f32x2, vf[dt][ct]));
        } else {
            f32x4 s[2][4];
#pragma unroll
            for (int qs = 0; qs < 2; ++qs)
#pragma unroll
                for (int ct = 0; ct < 4; ++ct) {
                    f32x4 z = {};
                    z = MFMA32K(kf[ct][0], qf[qs][0], z);
                    z = MFMA32K(kf[ct][1], qf[qs][1], z);
                    s[qs][ct] = z;
                }
            if constexpr (MODE == 1) {
#pragma unroll
                for (int qs = 0; qs < 2; ++qs)
#pragma unroll
                    for (int ct = 0; ct < 4; ++ct) keepf4(s[qs][ct]);
#pragma unroll
                for (int dt = 0; dt < 4; ++dt)
#pragma unroll
                    for (int ct = 0; ct < 4; ++ct)
                        keepf2(__builtin_bit_cast(f32x2, vf[dt][ct]));
            } else {
                const bool diag = (kt == nkv - 1);
                short4v pf[2][4];
#pragma unroll
                for (int qs = 0; qs < 2; ++qs) {
                    if (diag) {
#pragma unroll
                        for (int ct = 0; ct < 4; ++ct)
#pragma unroll
                            for (int r = 0; r < 4; ++r)
                                if (j0 + ct * 16 + 4 * h + r > qbase + qs * 16 + c)
                                    s[qs][ct][r] = -1e30f;
                    }
                    float lm = fmaxf(fmaxf(fmaxf(s[qs][0][0], s[qs][0][1]), fmaxf(s[qs][0][2], s[qs][0][3])),
                                     fmaxf(fmaxf(s[qs][1][0], s[qs][1][1]), fmaxf(s[qs][1][2], s[qs][1][3])));
                    lm = fmaxf(lm, fmaxf(fmaxf(fmaxf(s[qs][2][0], s[qs][2][1]), fmaxf(s[qs][2][2], s[qs][2][3])),
                                         fmaxf(fmaxf(s[qs][3][0], s[qs][3][1]), fmaxf(s[qs][3][2], s[qs][3][3]))));
                    // always-rescale (data-independent cost)
                    float rm = fmaxf(lm, __shfl_xor(lm, 16));
                    rm = fmaxf(rm, __shfl_xor(rm, 32));
                    float mn = fmaxf(m[qs], rm);
                    float sc = __builtin_amdgcn_exp2f(m[qs] - mn);
                    m[qs] = mn;
                    l[qs] *= sc;
#pragma unroll
                    for (int dt = 0; dt < 4; ++dt) o[qs][dt] *= sc;
                    float lsum = 0.0f;
#pragma unroll
                    for (int ct = 0; ct < 4; ++ct) {
                        bf16x4 pb;
#pragma unroll
                        for (int r = 0; r < 4; ++r) {
                            float p = __builtin_amdgcn_exp2f(s[qs][ct][r] - mn);
                            lsum += p;
                            pb[r] = (__bf16)p;
                        }
                        pf[qs][ct] = __builtin_bit_cast(short4v, pb);
                    }
                    l[qs] += lsum;
                }
                if constexpr (MODE == 2) {
#pragma unroll
                    for (int qs = 0; qs < 2; ++qs)
#pragma unroll
                        for (int ct = 0; ct < 4; ++ct)
                            keepf2(__builtin_bit_cast(f32x2, pf[qs][ct]));
#pragma unroll
                    for (int dt = 0; dt < 4; ++dt)
#pragma unroll
                        for (int ct = 0; ct < 4; ++ct)
                            keepf2(__builtin_bit_cast(f32x2, vf[dt][ct]));
                } else {
#pragma unroll
                    for (int qs = 0; qs < 2; ++qs)
#pragma unroll
                        for (int dt = 0; dt < 4; ++dt)
#pragma unroll
                            for (int ct = 0; ct < 4; ++ct)
                                o[qs][dt] = MFMA16K(vf[dt][ct], pf[qs][ct], o[qs][dt]);
                }
            }
        }
    }

    f32x4 a = o[0][0] + o[0][1] + o[0][2] + o[0][3] + o[1][0] + o[1][1] + o[1][2] + o[1][3];
    scratch[(size_t)blockIdx.x * 512 + tid] = a[0] + a[1] + a[2] + a[3] + m[0] + m[1] + l[0] + l[1];
}

// ---------------- launcher -------------------------------------------------
extern "C" void kernel_launch(void* const* d_in, const int* in_sizes, int n_in,
                              void* d_out, int out_size, void* d_ws, size_t ws_size,
                              hipStream_t stream) {
    const float* x  = (const float*)d_in[0];
    const float* Wq = (const float*)d_in[1];
    const float* Wk = (const float*)d_in[2];
    const float* Wv = (const float*)d_in[3];
    float* out = (float*)d_out;

    char* ws = (char*)d_ws;
    __bf16* Wb = (__bf16*)ws;                                  // 196608 B
    __bf16* Qb = (__bf16*)(ws + 196608);                       // 2097152 B
    __bf16* Kb = (__bf16*)(ws + 196608 + 2097152);             // 2097152 B
    __bf16* VF = (__bf16*)(ws + 196608 + 2 * 2097152);         // 2097152 B
    float* abl_scratch = (float*)Qb;  // recomputed by proj every launch

    wconv<<<dim3(128, 3), 256, 0, stream>>>(Wq, Wk, Wv, Wb);
    proj<<<512, 512, 0, stream>>>(x, Wb, Qb, Kb, VF);
    attn<<<512, 512, 0, stream>>>(Qb, Kb, VF, out);           // D (real, -> d_out)
    attn_abl<3><<<512, 512, 0, stream>>>(Qb, Kb, VF, abl_scratch);  // E compute-only
    attn_abl<2><<<512, 512, 0, stream>>>(Qb, Kb, VF, abl_scratch);  // C +softmax
    attn_abl<1><<<512, 512, 0, stream>>>(Qb, Kb, VF, abl_scratch);  // B +QK
    attn_abl<0><<<512, 512, 0, stream>>>(Qb, Kb, VF, abl_scratch);  // A loads-only
}

// Round 12
// 56.293 us; speedup vs baseline: 4.5375x; 4.5375x over previous
//
#include <hip/hip_runtime.h>

typedef float f32x4 __attribute__((ext_vector_type(4)));
typedef __bf16 bf16x8 __attribute__((ext_vector_type(8)));
typedef __bf16 bf16x4 __attribute__((ext_vector_type(4)));
typedef short short4v __attribute__((ext_vector_type(4)));

#define MFMA32K(a, b, c) __builtin_amdgcn_mfma_f32_16x16x32_bf16((a), (b), (c), 0, 0, 0)
#define MFMA16K(a, b, c) __builtin_amdgcn_mfma_f32_16x16x16bf16_1k((a), (b), (c), 0, 0, 0)
#define CFENCE() asm volatile("" ::: "memory")
#define DSFENCE() asm volatile("s_waitcnt lgkmcnt(0)" ::: "memory")

constexpr int Tn = 4096, Cn = 512, Hn = 64;
// fold C^-0.5 (reference scales by n_embed^-0.5) and log2(e) into Wq.
constexpr float QSCALE = 1.4426950408889634f * 0.04419417382415922f;
constexpr float M0 = -30000.0f;  // finite sentinel; exp2(x - M0) underflows to 0

// ---------------- kernel 0: W fp32 -> bf16 (Wq pre-scaled) ----------------
__global__ void wconv(const float* __restrict__ Wq, const float* __restrict__ Wk,
                      const float* __restrict__ Wv, __bf16* __restrict__ Wb) {
    int t = blockIdx.y;
    int i = blockIdx.x * 256 + threadIdx.x;
    const float* src = (t == 0) ? Wq : (t == 1) ? Wk : Wv;
    float scale = (t == 0) ? QSCALE : 1.0f;
    Wb[t * Hn * Cn + i] = (__bf16)(src[i] * scale);
}

// ---------------- kernel 1: QKV projection — canonical LDS-staged GEMM -----
// 256 blocks x 4 waves (1 block/CU). BM=64 tokens, BN=192 (all ch), BK=64,
// double-buffered LDS, T2 XOR-swizzle on A and B tiles (stride-128B reads
// would be 16-way bank conflicts), T14 issue-early/store-late staging.
// Wave = 16 tokens x 192 ch -> epilogue identical to R7's (verified layouts).
__global__ __launch_bounds__(256) void proj(const float* __restrict__ x,
                                            const __bf16* __restrict__ Wb,
                                            __bf16* __restrict__ Qb,
                                            __bf16* __restrict__ Kb,
                                            __bf16* __restrict__ VF) {
    const int tid = threadIdx.x;
    const int lane = tid & 63, wid = tid >> 6;
    const int c = lane & 15, h = lane >> 4;
    const int row0 = blockIdx.x * 64;

    // per buffer: A = 64x64 bf16 (8KB) at 0, B = 192x64 bf16 (24KB) at +8192B
    __shared__ __bf16 lds[2][16384];   // 64 KB total

    f32x4 acc[12] = {};                // 12 ch-frags x 16 tokens
    float4 xl[4];                      // staged x (fp32)
    bf16x8 wl[6];                      // staged W (bf16)

    auto load_x = [&](int ks) {
#pragma unroll
        for (int p = 0; p < 4; ++p) {
            int g = tid + p * 256;
            int row = g >> 4, cidx = g & 15;
            xl[p] = *(const float4*)(x + (size_t)(row0 + row) * Cn + ks * 64 + cidx * 4);
        }
    };
    auto load_w = [&](int ks) {
#pragma unroll
        for (int s = 0; s < 6; ++s) {
            int L = tid + s * 256;
            int ch = L >> 3, q = L & 7;
            wl[s] = *(const bf16x8*)(Wb + (size_t)ch * Cn + ks * 64 + q * 8);
        }
    };
    auto store_buf = [&](int buf) {
        char* base = (char*)lds[buf];
#pragma unroll
        for (int p = 0; p < 4; ++p) {
            int g = tid + p * 256;
            int row = g >> 4, cidx = g & 15;
            bf16x4 b;
            b[0] = (__bf16)xl[p].x; b[1] = (__bf16)xl[p].y;
            b[2] = (__bf16)xl[p].z; b[3] = (__bf16)xl[p].w;
            // 16B-chunk XOR swizzle within the 128B row (T2)
            *(bf16x4*)(base + row * 128 +
                       ((((cidx >> 1) ^ (row & 7)) << 4) | ((cidx & 1) << 3))) = b;
        }
        char* bb = base + 8192;
#pragma unroll
        for (int s = 0; s < 6; ++s) {
            int L = tid + s * 256;
            int ch = L >> 3, q = L & 7;
            *(bf16x8*)(bb + ch * 128 + ((q ^ (ch & 7)) << 4)) = wl[s];
        }
    };

    load_x(0); load_w(0);
    store_buf(0);
    __syncthreads();

    for (int ks = 0; ks < 8; ++ks) {
        const int cur = ks & 1;
        if (ks < 7) { load_x(ks + 1); load_w(ks + 1); }  // issue early (T14)
        const char* A = (const char*)lds[cur];
        const char* B = A + 8192;
#pragma unroll
        for (int k = 0; k < 2; ++k) {
            // A-frag: token row = wid*16+c, K chunk (4k+h), same XOR on read
            bf16x8 af = *(const bf16x8*)(A + (wid * 16 + c) * 128 +
                                         (((4 * k + h) ^ (c & 7)) << 4));
#pragma unroll
            for (int j = 0; j < 12; ++j) {
                int ch = j * 16 + c;
                bf16x8 bf = *(const bf16x8*)(B + ch * 128 +
                                             (((4 * k + h) ^ (ch & 7)) << 4));
                acc[j] = MFMA32K(af, bf, acc[j]);
            }
        }
        if (ks < 7) store_buf(cur ^ 1);                  // write late (T14)
        __syncthreads();
    }

    // ---- epilogue (verified R7 layouts; tb aliases loop LDS after barrier)
    __bf16(*tb)[16][72] = (__bf16(*)[16][72])lds[0];
#pragma unroll
    for (int w = 0; w < 2; ++w) {
        CFENCE();
#pragma unroll
        for (int nt = 0; nt < 4; ++nt)
#pragma unroll
            for (int r = 0; r < 4; ++r)
                tb[wid][h * 4 + r][nt * 16 + c] = (__bf16)acc[w * 4 + nt][r];
        DSFENCE();
        __bf16* dst = (w == 0) ? Qb : Kb;
#pragma unroll
        for (int ch2 = 0; ch2 < 2; ++ch2) {
            int rr = ch2 * 8 + (lane >> 3);
            bf16x8 vv = *(const bf16x8*)(&tb[wid][rr][(lane & 7) * 8]);
            *(bf16x8*)(dst + (size_t)(row0 + wid * 16 + rr) * Hn + (lane & 7) * 8) = vv;
        }
        CFENCE();
    }
    // V -> fragment-major VF[b][tile][h][d][4] (direct, lane holds 4 tokens)
    const int rowv = row0 + wid * 16;
    const int b = rowv >> 12;
    const int t0 = rowv & (Tn - 1);
    const int tile = t0 >> 4;
#pragma unroll
    for (int nt = 0; nt < 4; ++nt) {
        f32x4 a = acc[8 + nt];
        bf16x4 v4;
        v4[0] = (__bf16)a.x; v4[1] = (__bf16)a.y;
        v4[2] = (__bf16)a.z; v4[3] = (__bf16)a.w;
        size_t off = ((size_t)((b * 256 + tile) * 4 + h) * 64 + (nt * 16 + c)) * 4;
        *(bf16x4*)(VF + off) = v4;
    }
}

// ---------------- kernel 2: causal flash attention (R6 verbatim, ~20us) ----
// 256 blocks x 8 waves, plain lb(512) — needs ~160+ VGPR, NO min-waves clause
// (R7/R8/R9: any forced cap spills to scratch/HBM, 2-5x regression).
__global__ __launch_bounds__(512) void attn(const __bf16* __restrict__ Qb,
                                            const __bf16* __restrict__ Kb,
                                            const __bf16* __restrict__ VF,
                                            float* __restrict__ out) {
    const int tid = threadIdx.x;
    const int lane = tid & 63, ks = tid >> 6;
    const int c = lane & 15, h = lane >> 4;
    const int b = blockIdx.x & 3;
    const int v = blockIdx.x >> 2;               // 0..63

    const __bf16* Kbase = Kb + (size_t)b * Tn * Hn;
    const __bf16* Vbase = VF + (size_t)b * 256 * 1024;

    __shared__ float Mo[4][64][36];
    __shared__ float Mml[4][64][4];

#pragma unroll 1
    for (int grp = 0; grp < 2; ++grp) {
        const int vg = grp ? (127 - v) : v;
        const int qbase = vg * 32;
        const int nkv = vg / 2 + 1;

        bf16x8 qf[2][2];
#pragma unroll
        for (int qs = 0; qs < 2; ++qs) {
            const __bf16* qp = Qb + (size_t)(b * Tn + qbase + qs * 16 + c) * Hn;
            qf[qs][0] = *(const bf16x8*)(qp + 8 * h);
            qf[qs][1] = *(const bf16x8*)(qp + 32 + 8 * h);
        }

        f32x4 o[2][4] = {};
        float m[2] = {M0, M0};
        float l[2] = {};

        bf16x8 kfc[4][2];
        {
            const int kt0 = (ks < nkv) ? ks : nkv - 1;
#pragma unroll
            for (int ct = 0; ct < 4; ++ct) {
                const __bf16* kp = Kbase + (size_t)(kt0 * 64 + ct * 16 + c) * Hn;
                kfc[ct][0] = *(const bf16x8*)(kp + 8 * h);
                kfc[ct][1] = *(const bf16x8*)(kp + 32 + 8 * h);
            }
        }

        for (int kt = ks; kt < nkv; kt += 8) {
            const int j0 = kt * 64;
            bf16x8 kfn[4][2];
            {
                const int ktn = (kt + 8 < nkv) ? kt + 8 : kt;
#pragma unroll
                for (int ct = 0; ct < 4; ++ct) {
                    const __bf16* kp = Kbase + (size_t)(ktn * 64 + ct * 16 + c) * Hn;
                    kfn[ct][0] = *(const bf16x8*)(kp + 8 * h);
                    kfn[ct][1] = *(const bf16x8*)(kp + 32 + 8 * h);
                }
            }
            short4v vf[4][4];
            const __bf16* vt = Vbase + ((size_t)(j0 >> 4) << 10) + (h << 8);
#pragma unroll
            for (int dt = 0; dt < 4; ++dt)
#pragma unroll
                for (int ct = 0; ct < 4; ++ct)
                    vf[dt][ct] = *(const short4v*)(vt + (ct << 10) + ((dt * 16 + c) << 2));

            const bool diag = (kt == nkv - 1);

#pragma unroll
            for (int qs = 0; qs < 2; ++qs) {
                f32x4 s[4];
#pragma unroll
                for (int ct = 0; ct < 4; ++ct) {
                    f32x4 z = {};
                    z = MFMA32K(kfc[ct][0], qf[qs][0], z);
                    z = MFMA32K(kfc[ct][1], qf[qs][1], z);
                    s[ct] = z;
                }
                if (diag) {
#pragma unroll
                    for (int ct = 0; ct < 4; ++ct)
#pragma unroll
                        for (int r = 0; r < 4; ++r)
                            if (j0 + ct * 16 + 4 * h + r > qbase + qs * 16 + c)
                                s[ct][r] = -1e30f;
                }
                float lm = fmaxf(fmaxf(fmaxf(s[0][0], s[0][1]), fmaxf(s[0][2], s[0][3])),
                                 fmaxf(fmaxf(s[1][0], s[1][1]), fmaxf(s[1][2], s[1][3])));
                lm = fmaxf(lm, fmaxf(fmaxf(fmaxf(s[2][0], s[2][1]), fmaxf(s[2][2], s[2][3])),
                                     fmaxf(fmaxf(s[3][0], s[3][1]), fmaxf(s[3][2], s[3][3]))));
                if (!__all(lm <= m[qs] + 8.0f)) {
                    float rm = fmaxf(lm, __shfl_xor(lm, 16));
                    rm = fmaxf(rm, __shfl_xor(rm, 32));
                    float mn = fmaxf(m[qs], rm);
                    float sc = __builtin_amdgcn_exp2f(m[qs] - mn);
                    m[qs] = mn;
                    l[qs] *= sc;
#pragma unroll
                    for (int dt = 0; dt < 4; ++dt) o[qs][dt] *= sc;
                }
                short4v pf[4];
                float lsum = 0.0f;
#pragma unroll
                for (int ct = 0; ct < 4; ++ct) {
                    bf16x4 pb;
#pragma unroll
                    for (int r = 0; r < 4; ++r) {
                        float p = __builtin_amdgcn_exp2f(s[ct][r] - m[qs]);
                        lsum += p;
                        pb[r] = (__bf16)p;
                    }
                    pf[ct] = __builtin_bit_cast(short4v, pb);
                }
                l[qs] += lsum;
#pragma unroll
                for (int dt = 0; dt < 4; ++dt)
#pragma unroll
                    for (int ct = 0; ct < 4; ++ct)
                        o[qs][dt] = MFMA16K(vf[dt][ct], pf[ct], o[qs][dt]);
            }
#pragma unroll
            for (int ct = 0; ct < 4; ++ct) {
                kfc[ct][0] = kfn[ct][0];
                kfc[ct][1] = kfn[ct][1];
            }
        }

#pragma unroll
        for (int qs = 0; qs < 2; ++qs) {
            l[qs] += __shfl_xor(l[qs], 16);
            l[qs] += __shfl_xor(l[qs], 32);
        }

#pragma unroll
        for (int step = 4; step >= 1; step >>= 1) {
            if (ks >= step && ks < 2 * step) {
                int slot = ks - step;
#pragma unroll
                for (int qs = 0; qs < 2; ++qs) {
                    Mml[slot][lane][qs] = m[qs];
                    Mml[slot][lane][2 + qs] = l[qs];
#pragma unroll
                    for (int dt = 0; dt < 4; ++dt)
                        *(f32x4*)&Mo[slot][lane][(qs * 4 + dt) * 4] = o[qs][dt];
                }
            }
            __syncthreads();
            if (ks < step) {
#pragma unroll
                for (int qs = 0; qs < 2; ++qs) {
                    float m2 = Mml[ks][lane][qs];
                    float l2 = Mml[ks][lane][2 + qs];
                    float M = fmaxf(m[qs], m2);
                    float e1 = __builtin_amdgcn_exp2f(m[qs] - M);
                    float e2 = __builtin_amdgcn_exp2f(m2 - M);
                    m[qs] = M;
                    l[qs] = l[qs] * e1 + l2 * e2;
#pragma unroll
                    for (int dt = 0; dt < 4; ++dt) {
                        f32x4 o2 = *(const f32x4*)&Mo[ks][lane][(qs * 4 + dt) * 4];
                        o[qs][dt] = o[qs][dt] * e1 + o2 * e2;
                    }
                }
            }
            __syncthreads();
        }

        if (ks == 0) {
#pragma unroll
            for (int qs = 0; qs < 2; ++qs) {
                float rl = 1.0f / l[qs];
                float* ob = out + ((size_t)(b * Tn + qbase + qs * 16 + c)) * Hn;
#pragma unroll
                for (int dt = 0; dt < 4; ++dt) {
                    f32x4 w = o[qs][dt] * rl;
                    *(f32x4*)(ob + dt * 16 + 4 * h) = w;
                }
            }
        }
    }
}

// ---------------- launcher -------------------------------------------------
extern "C" void kernel_launch(void* const* d_in, const int* in_sizes, int n_in,
                              void* d_out, int out_size, void* d_ws, size_t ws_size,
                              hipStream_t stream) {
    const float* x  = (const float*)d_in[0];
    const float* Wq = (const float*)d_in[1];
    const float* Wk = (const float*)d_in[2];
    const float* Wv = (const float*)d_in[3];
    float* out = (float*)d_out;

    char* ws = (char*)d_ws;
    __bf16* Wb = (__bf16*)ws;                                  // 196608 B
    __bf16* Qb = (__bf16*)(ws + 196608);                       // 2097152 B
    __bf16* Kb = (__bf16*)(ws + 196608 + 2097152);             // 2097152 B
    __bf16* VF = (__bf16*)(ws + 196608 + 2 * 2097152);         // 2097152 B

    wconv<<<dim3(128, 3), 256, 0, stream>>>(Wq, Wk, Wv, Wb);
    proj<<<256, 256, 0, stream>>>(x, Wb, Qb, Kb, VF);
    attn<<<256, 512, 0, stream>>>(Qb, Kb, VF, out);
}